// Round 4
// baseline (476.373 us; speedup 1.0000x reference)
//
#include <hip/hip_runtime.h>

typedef __attribute__((ext_vector_type(8))) short bf16x8;
typedef __attribute__((ext_vector_type(4))) float f32x4;
typedef unsigned short u16;
typedef unsigned int u32;

#define NTOK 144
#define CDIM 192
#define NH 6
#define CH 32
#define C3 576
#define NWIN 64
#define WLON 15
#define SCALE 0.17677669529663687f
#define LOG2E 1.4426950408889634f

// ws layout (bytes)
#define OFF_W1T  0u            // 576*192*2 = 221184
#define OFF_W2T  221184u       // 192*192*2 = 73728
#define OFF_COMB 294912u       // 384*81*64*4*2 = 15925248 (frag layout)

__device__ __forceinline__ u16 f2b(float f){
  u32 u = __float_as_uint(f);
  u32 r = u + 0x7FFFu + ((u >> 16) & 1u);   // RNE
  return (u16)(r >> 16);
}
__device__ __forceinline__ float b2f(u16 u){
  return __uint_as_float(((u32)u) << 16);
}
__device__ __forceinline__ u32 pk2(float a, float b){
  return (u32)f2b(a) | ((u32)f2b(b) << 16);
}

// ---------------- prep: transpose weights to bf16 (B-operand wants k-contiguous rows)
extern "C" __global__ __launch_bounds__(256) void prep_weights(
    const float* __restrict__ w1, const float* __restrict__ w2,
    u16* __restrict__ w1t, u16* __restrict__ w2t){
  int idx = blockIdx.x * 256 + threadIdx.x;
  if (idx < CDIM * C3){ int k = idx / C3;  int c = idx - k * C3;  w1t[c * CDIM + k] = f2b(w1[idx]); }
  if (idx < CDIM * CDIM){ int k = idx / CDIM; int c = idx - k * CDIM; w2t[c * CDIM + k] = f2b(w2[idx]); }
}

// ---------------- prep: comb in MFMA C-fragment layout:
// comb[nwh][ti(9)][nt(9)][lane(64)][r(4)] = bias_table[pidx[i*144+j]][nw][h] + mask[nw*15][i][j]
extern "C" __global__ __launch_bounds__(192) void prep_comb(
    const float* __restrict__ bt, const float* __restrict__ mask,
    const int* __restrict__ pidx, u16* __restrict__ comb){
  int nwh = blockIdx.x;                 // 0..383 = nw*6+h
  int nw = nwh / NH, h = nwh - nw * NH;
  int tl = blockIdx.y * 192 + threadIdx.x;   // 0..5183 = (ti*9+nt)*64+lane
  int ti = tl / 576;
  int rem = tl - ti * 576;
  int nt = rem >> 6, lane = rem & 63;
  int ib = ti * 16 + ((lane >> 4) << 2);
  int j  = nt * 16 + (lane & 15);
  const float* mrow = mask + (size_t)(nw * WLON) * (NTOK * NTOK);
  float v[4];
  #pragma unroll
  for (int r = 0; r < 4; ++r){
    int e = (ib + r) * NTOK + j;
    int pi = pidx[e];
    v[r] = bt[((size_t)pi * NWIN + nw) * NH + h] + mrow[e];
  }
  uint2 out; out.x = pk2(v[0], v[1]); out.y = pk2(v[2], v[3]);
  *reinterpret_cast<uint2*>(comb + ((size_t)nwh * 5184 + tl) * 4) = out;
}

// ---------------- K1: fused qkv + attention, one block per window.
// 3 waves x 48 rows. A-frags of x register-resident (converted once). Per head:
// compute q/k/v (B-frags from L2-resident w1t), stage Q (per-wave) / K / V^T in LDS,
// then windowed attention exactly as the proven R2 path. Stash bf16 -> d_out upper half.
#define QKPAD 40    // 80B rows: 16B-aligned, 8 bank-quads over 16 lanes (2-way = free)
#define VPAD  168   // 336B rows: 16B-aligned, 8 bank-quads
extern "C" __global__ __launch_bounds__(192, 3) void fused_qkv_attn(
    const float* __restrict__ x, const u16* __restrict__ w1t, const float* __restrict__ b1,
    const u16* __restrict__ comb, float* __restrict__ outbuf){
  __shared__ u16 Kl[NTOK * QKPAD];      // [token][ch]   11520 B
  __shared__ u16 Vt[CH * VPAD];         // [ch][token]   10752 B (token pad 144..167 zeroed)
  __shared__ u16 Qw[3][48 * QKPAD];     // per-wave Q    11520 B
  __shared__ u16 Pl[3][16 * QKPAD];     // per-wave P     3840 B
  const int tid = threadIdx.x;
  const int b = blockIdx.x;
  const int wv = tid >> 6, lane = tid & 63, l15 = lane & 15, l4 = lane >> 4;
  const f32x4 zz = {0.f, 0.f, 0.f, 0.f};

  // A fragments: rows wv*48 + mi*16 + l15, k = kk*32 + l4*8 ; fp32 -> bf16 once
  bf16x8 af[3][6];
  const float* xw = x + ((size_t)b * NTOK + wv * 48 + l15) * CDIM + l4 * 8;
  #pragma unroll
  for (int mi = 0; mi < 3; ++mi){
    #pragma unroll
    for (int kk = 0; kk < 6; ++kk){
      float4 f0 = *reinterpret_cast<const float4*>(xw + mi * 16 * CDIM + kk * 32);
      float4 f1 = *reinterpret_cast<const float4*>(xw + mi * 16 * CDIM + kk * 32 + 4);
      union { bf16x8 v; uint4 u; } cv;
      cv.u.x = pk2(f0.x, f0.y); cv.u.y = pk2(f0.z, f0.w);
      cv.u.z = pk2(f1.x, f1.y); cv.u.w = pk2(f1.z, f1.w);
      af[mi][kk] = cv.v;
    }
  }
  // zero Vt token-pad once (cols 144..167); PV tail then needs no clamp/zeroing
  for (int e = tid; e < CH * (VPAD - NTOK); e += 192)
    Vt[(e / (VPAD - NTOK)) * VPAD + NTOK + (e % (VPAD - NTOK))] = 0;

  u16* stash = reinterpret_cast<u16*>(outbuf);

  for (int h = 0; h < NH; ++h){
    __syncthreads();   // prior head's K/V reads done (h=0: pad zeros visible)
    // this head's bias values (per output col)
    const float bq0 = b1[h * 32 + l15],        bq1 = b1[h * 32 + 16 + l15];
    const float bk0 = b1[192 + h * 32 + l15],  bk1 = b1[192 + h * 32 + 16 + l15];
    const float bv0 = b1[384 + h * 32 + l15],  bv1 = b1[384 + h * 32 + 16 + l15];
    #pragma unroll 1
    for (int mi = 0; mi < 3; ++mi){
      f32x4 qa0 = zz, qa1 = zz, ka0 = zz, ka1 = zz, va0 = zz, va1 = zz;
      #pragma unroll
      for (int kk = 0; kk < 6; ++kk){
        const u16* wp = w1t + kk * 32 + l4 * 8;
        bf16x8 wq0 = *reinterpret_cast<const bf16x8*>(wp + (size_t)(h * 32 + l15) * CDIM);
        bf16x8 wq1 = *reinterpret_cast<const bf16x8*>(wp + (size_t)(h * 32 + 16 + l15) * CDIM);
        bf16x8 wk0 = *reinterpret_cast<const bf16x8*>(wp + (size_t)(192 + h * 32 + l15) * CDIM);
        bf16x8 wk1 = *reinterpret_cast<const bf16x8*>(wp + (size_t)(192 + h * 32 + 16 + l15) * CDIM);
        bf16x8 wv0 = *reinterpret_cast<const bf16x8*>(wp + (size_t)(384 + h * 32 + l15) * CDIM);
        bf16x8 wv1 = *reinterpret_cast<const bf16x8*>(wp + (size_t)(384 + h * 32 + 16 + l15) * CDIM);
        qa0 = __builtin_amdgcn_mfma_f32_16x16x32_bf16(af[mi][kk], wq0, qa0, 0, 0, 0);
        qa1 = __builtin_amdgcn_mfma_f32_16x16x32_bf16(af[mi][kk], wq1, qa1, 0, 0, 0);
        ka0 = __builtin_amdgcn_mfma_f32_16x16x32_bf16(af[mi][kk], wk0, ka0, 0, 0, 0);
        ka1 = __builtin_amdgcn_mfma_f32_16x16x32_bf16(af[mi][kk], wk1, ka1, 0, 0, 0);
        va0 = __builtin_amdgcn_mfma_f32_16x16x32_bf16(af[mi][kk], wv0, va0, 0, 0, 0);
        va1 = __builtin_amdgcn_mfma_f32_16x16x32_bf16(af[mi][kk], wv1, va1, 0, 0, 0);
      }
      const int tr = mi * 16 + l4 * 4;      // within-wave row; global token = wv*48 + tr
      #pragma unroll
      for (int r = 0; r < 4; ++r){
        Qw[wv][(tr + r) * QKPAD + l15]      = f2b((qa0[r] + bq0) * SCALE);
        Qw[wv][(tr + r) * QKPAD + 16 + l15] = f2b((qa1[r] + bq1) * SCALE);
        int gt = wv * 48 + tr + r;
        Kl[gt * QKPAD + l15]      = f2b(ka0[r] + bk0);
        Kl[gt * QKPAD + 16 + l15] = f2b(ka1[r] + bk1);
        Vt[l15 * VPAD + gt]        = f2b(va0[r] + bv0);
        Vt[(16 + l15) * VPAD + gt] = f2b(va1[r] + bv1);
      }
    }
    __syncthreads();   // K/V complete for all waves
    const size_t cbase = ((size_t)((b / WLON) * NH + h)) * (5184 * 4);  // u16 units
    u16* Pw = Pl[wv];
    #pragma unroll 1
    for (int mi = 0; mi < 3; ++mi){
      const int ti = wv * 3 + mi;
      bf16x8 aq = *reinterpret_cast<const bf16x8*>(Qw[wv] + (mi * 16 + l15) * QKPAD + l4 * 8);
      f32x4 s[9];
      #pragma unroll
      for (int nt = 0; nt < 9; ++nt){
        bf16x8 bk = *reinterpret_cast<const bf16x8*>(Kl + (nt * 16 + l15) * QKPAD + l4 * 8);
        s[nt] = __builtin_amdgcn_mfma_f32_16x16x32_bf16(aq, bk, zz, 0, 0, 0);
      }
      #pragma unroll
      for (int nt = 0; nt < 9; ++nt){
        uint2 cc = *reinterpret_cast<const uint2*>(comb + cbase + ((size_t)(ti * 9 + nt) * 64 + lane) * 4);
        s[nt][0] += b2f((u16)(cc.x & 0xFFFF));
        s[nt][1] += b2f((u16)(cc.x >> 16));
        s[nt][2] += b2f((u16)(cc.y & 0xFFFF));
        s[nt][3] += b2f((u16)(cc.y >> 16));
      }
      float invs[4];
      #pragma unroll
      for (int r = 0; r < 4; ++r){
        float mx = s[0][r];
        #pragma unroll
        for (int nt = 1; nt < 9; ++nt) mx = fmaxf(mx, s[nt][r]);
        #pragma unroll
        for (int off = 8; off; off >>= 1) mx = fmaxf(mx, __shfl_xor(mx, off, 16));
        float sum = 0.f;
        #pragma unroll
        for (int nt = 0; nt < 9; ++nt){
          float p = exp2f((s[nt][r] - mx) * LOG2E);
          s[nt][r] = p; sum += p;
        }
        #pragma unroll
        for (int off = 8; off; off >>= 1) sum += __shfl_xor(sum, off, 16);
        invs[r] = 1.0f / sum;   // applied at stash
      }
      // PV through per-wave P chunk; V-pad cols are zero so tail contributes exact 0
      f32x4 o0 = zz, o1 = zz;
      #pragma unroll
      for (int kk = 0; kk < 5; ++kk){
        #pragma unroll
        for (int r = 0; r < 4; ++r){
          Pw[(l4 * 4 + r) * QKPAD + l15] = f2b(s[2 * kk][r]);
          if (kk < 4) Pw[(l4 * 4 + r) * QKPAD + 16 + l15] = f2b(s[2 * kk + 1][r]);
        }
        bf16x8 ap  = *reinterpret_cast<const bf16x8*>(Pw + l15 * QKPAD + l4 * 8);
        bf16x8 bv0_ = *reinterpret_cast<const bf16x8*>(Vt + l15 * VPAD + kk * 32 + l4 * 8);
        bf16x8 bv1_ = *reinterpret_cast<const bf16x8*>(Vt + (16 + l15) * VPAD + kk * 32 + l4 * 8);
        o0 = __builtin_amdgcn_mfma_f32_16x16x32_bf16(ap, bv0_, o0, 0, 0, 0);
        o1 = __builtin_amdgcn_mfma_f32_16x16x32_bf16(ap, bv1_, o1, 0, 0, 0);
      }
      #pragma unroll
      for (int r = 0; r < 4; ++r){
        size_t t = (size_t)b * NTOK + ti * 16 + l4 * 4 + r;
        float is = invs[r];
        stash[t * 384 + 192 + h * CH + l15]      = f2b(o0[r] * is);
        stash[t * 384 + 192 + h * CH + 16 + l15] = f2b(o1[r] * is);
      }
    }
  }
}

// ---------------- K2: out = attn_out @ w2 + b2 — B register-stationary, zero LDS/barriers.
// Block = (256 rows, 96-col half). Each wave holds 36 w2t frags (loaded once),
// streams 4 m-tiles: 6 independent A-loads -> 36 MFMAs each.
extern "C" __global__ __launch_bounds__(256, 2) void proj_gemm(
    const u16* __restrict__ w2t, const float* __restrict__ b2, float* __restrict__ outbuf){
  const int tid = threadIdx.x;
  const int wid = tid >> 6, lane = tid & 63, l15 = lane & 15, l4 = lane >> 4;
  const int hb = blockIdx.y;             // col half: cols hb*96 .. +96
  const f32x4 zz = {0.f, 0.f, 0.f, 0.f};

  bf16x8 bfr[6][6];
  #pragma unroll
  for (int nf = 0; nf < 6; ++nf)
    #pragma unroll
    for (int kk = 0; kk < 6; ++kk)
      bfr[nf][kk] = *reinterpret_cast<const bf16x8*>(
          w2t + (size_t)(hb * 96 + nf * 16 + l15) * CDIM + kk * 32 + l4 * 8);

  const u16* stash = reinterpret_cast<const u16*>(outbuf);
  #pragma unroll 1
  for (int mt = 0; mt < 4; ++mt){
    const size_t r0 = (size_t)blockIdx.x * 256 + wid * 64 + mt * 16;
    bf16x8 afr[6];
    const u16* src = stash + (r0 + l15) * 384 + 192 + l4 * 8;
    #pragma unroll
    for (int kk = 0; kk < 6; ++kk)
      afr[kk] = *reinterpret_cast<const bf16x8*>(src + kk * 32);
    f32x4 acc[6];
    #pragma unroll
    for (int nf = 0; nf < 6; ++nf) acc[nf] = zz;
    #pragma unroll
    for (int kk = 0; kk < 6; ++kk)
      #pragma unroll
      for (int nf = 0; nf < 6; ++nf)
        acc[nf] = __builtin_amdgcn_mfma_f32_16x16x32_bf16(afr[kk], bfr[nf][kk], acc[nf], 0, 0, 0);
    #pragma unroll
    for (int nf = 0; nf < 6; ++nf){
      int c = hb * 96 + nf * 16 + l15;
      float bias = b2[c];
      #pragma unroll
      for (int r = 0; r < 4; ++r)
        outbuf[(r0 + l4 * 4 + r) * CDIM + c] = acc[nf][r] + bias;
    }
  }
}

extern "C" void kernel_launch(void* const* d_in, const int* in_sizes, int n_in,
                              void* d_out, int out_size, void* d_ws, size_t ws_size,
                              hipStream_t stream){
  const float* x    = (const float*)d_in[0];
  const float* w1   = (const float*)d_in[1];
  const float* b1   = (const float*)d_in[2];
  const float* w2   = (const float*)d_in[3];
  const float* b2   = (const float*)d_in[4];
  const float* bt   = (const float*)d_in[5];
  const float* mask = (const float*)d_in[6];
  const int*   pidx = (const int*)d_in[7];
  (void)in_sizes; (void)n_in; (void)out_size; (void)ws_size;

  char* ws = (char*)d_ws;
  u16* w1t  = (u16*)(ws + OFF_W1T);
  u16* w2t  = (u16*)(ws + OFF_W2T);
  u16* comb = (u16*)(ws + OFF_COMB);
  float* out = (float*)d_out;

  prep_weights<<<dim3(432), dim3(256), 0, stream>>>(w1, w2, w1t, w2t);
  prep_comb<<<dim3(384, 27), dim3(192), 0, stream>>>(bt, mask, pidx, comb);
  fused_qkv_attn<<<dim3(960), dim3(192), 0, stream>>>(x, w1t, b1, comb, out);
  proj_gemm<<<dim3(540, 2), dim3(256), 0, stream>>>(w2t, b2, out);
}

// Round 5
// 290.527 us; speedup vs baseline: 1.6397x; 1.6397x over previous
//
#include <hip/hip_runtime.h>

typedef __attribute__((ext_vector_type(8))) short bf16x8;
typedef __attribute__((ext_vector_type(4))) float f32x4;
typedef unsigned short u16;
typedef unsigned int u32;

#define NTOK 144
#define CDIM 192
#define NH 6
#define CH 32
#define C3 576
#define NWIN 64
#define WLON 15
#define SCALE 0.17677669529663687f
#define LOG2E 1.4426950408889634f

// ws layout (bytes)
#define OFF_W1T  0u            // 576*192*2 = 221184
#define OFF_W2T  221184u       // 192*192*2 = 73728
#define OFF_COMB 294912u       // 384*81*64*4*2 = 15925248 (frag layout)
#define OFF_Q    16220160u     // 960*6*144*32*2 = 53084160
#define OFF_K    69304320u
#define OFF_V    122388480u    // stored transposed: [b][h][ch][144]

__device__ __forceinline__ u16 f2b(float f){
  u32 u = __float_as_uint(f);
  u32 r = u + 0x7FFFu + ((u >> 16) & 1u);   // RNE
  return (u16)(r >> 16);
}
__device__ __forceinline__ float b2f(u16 u){
  return __uint_as_float(((u32)u) << 16);
}
__device__ __forceinline__ u32 pk2(float a, float b){
  return (u32)f2b(a) | ((u32)f2b(b) << 16);
}

// ---------------- prep: transpose weights to bf16 (B-operand wants k-contiguous rows)
extern "C" __global__ __launch_bounds__(256) void prep_weights(
    const float* __restrict__ w1, const float* __restrict__ w2,
    u16* __restrict__ w1t, u16* __restrict__ w2t){
  int idx = blockIdx.x * 256 + threadIdx.x;
  if (idx < CDIM * C3){ int k = idx / C3;  int c = idx - k * C3;  w1t[c * CDIM + k] = f2b(w1[idx]); }
  if (idx < CDIM * CDIM){ int k = idx / CDIM; int c = idx - k * CDIM; w2t[c * CDIM + k] = f2b(w2[idx]); }
}

// ---------------- prep: comb in MFMA C-fragment layout:
// comb[nwh][ti(9)][nt(9)][lane(64)][r(4)] = bias_table[pidx[i*144+j]][nw][h] + mask[nw*15][i][j]
extern "C" __global__ __launch_bounds__(192) void prep_comb(
    const float* __restrict__ bt, const float* __restrict__ mask,
    const int* __restrict__ pidx, u16* __restrict__ comb){
  int nwh = blockIdx.x;                 // 0..383 = nw*6+h
  int nw = nwh / NH, h = nwh - nw * NH;
  int tl = blockIdx.y * 192 + threadIdx.x;   // 0..5183 = (ti*9+nt)*64+lane
  int ti = tl / 576;
  int rem = tl - ti * 576;
  int nt = rem >> 6, lane = rem & 63;
  int ib = ti * 16 + ((lane >> 4) << 2);
  int j  = nt * 16 + (lane & 15);
  const float* mrow = mask + (size_t)(nw * WLON) * (NTOK * NTOK);
  float v[4];
  #pragma unroll
  for (int r = 0; r < 4; ++r){
    int e = (ib + r) * NTOK + j;
    int pi = pidx[e];
    v[r] = bt[((size_t)pi * NWIN + nw) * NH + h] + mrow[e];
  }
  uint2 out; out.x = pk2(v[0], v[1]); out.y = pk2(v[2], v[3]);
  *reinterpret_cast<uint2*>(comb + ((size_t)nwh * 5184 + tl) * 4) = out;
}

// ---------------- K1: qkv = x @ w1 + b1 — A register-resident per wave, B LDS double-buffered.
// Stage nt+1's 64x192 B-panel while computing nt (one barrier per nt). Pad 200 -> conflict-free.
#define BPAD 200
extern "C" __global__ __launch_bounds__(256, 3) void qkv_gemm(
    const float* __restrict__ x, const u16* __restrict__ w1t, const float* __restrict__ b1,
    u16* __restrict__ qw, u16* __restrict__ kw, u16* __restrict__ vw){
  __shared__ u16 Bl[2][64 * BPAD];   // 2 x 25.6 KB
  const int tid = threadIdx.x;
  const int wid = tid >> 6, lane = tid & 63, l15 = lane & 15, l4 = lane >> 4;
  const size_t row0 = (size_t)blockIdx.x * 128 + wid * 32;
  const f32x4 zz = {0.f, 0.f, 0.f, 0.f};

  // A fragments: rows row0 + mf*16 + l15, k = kk*32 + l4*8 (2x float4 -> bf16x8, once)
  bf16x8 af[2][6];
  #pragma unroll
  for (int mf = 0; mf < 2; ++mf){
    const float* src = x + (row0 + mf * 16 + l15) * CDIM + l4 * 8;
    #pragma unroll
    for (int kk = 0; kk < 6; ++kk){
      float4 f0 = *reinterpret_cast<const float4*>(src + kk * 32);
      float4 f1 = *reinterpret_cast<const float4*>(src + kk * 32 + 4);
      union { bf16x8 v; uint4 u; } cv;
      cv.u.x = pk2(f0.x, f0.y); cv.u.y = pk2(f0.z, f0.w);
      cv.u.z = pk2(f1.x, f1.y); cv.u.w = pk2(f1.z, f1.w);
      af[mf][kk] = cv.v;
    }
  }
  // hoisted output-row decomposition (quads never straddle windows: 4 | 144)
  int bw_[2], n0_[2];
  #pragma unroll
  for (int mf = 0; mf < 2; ++mf){
    int t0 = (int)row0 + mf * 16 + l4 * 4;
    bw_[mf] = t0 / NTOK; n0_[mf] = t0 - bw_[mf] * NTOK;
  }

  const int sr = tid >> 2, sq = tid & 3;      // staging role: 4 threads/row, 48 u16 each
  // stage nt=0 into Bl[0]
  {
    const u16* src = w1t + (size_t)sr * CDIM + sq * 48;
    u16* dst = &Bl[0][sr * BPAD + sq * 48];
    #pragma unroll
    for (int i = 0; i < 48; i += 8)
      *reinterpret_cast<uint4*>(dst + i) = *reinterpret_cast<const uint4*>(src + i);
  }

  int cur = 0;
  #pragma unroll 1
  for (int nt = 0; nt < 9; ++nt){
    __syncthreads();   // stage(nt) visible; Bl[cur^1] free (nt-1 compute done)
    if (nt < 8){       // stage next panel into the other buffer (overlaps this nt's MFMAs)
      const u16* src = w1t + (size_t)((nt + 1) * 64 + sr) * CDIM + sq * 48;
      u16* dst = &Bl[cur ^ 1][sr * BPAD + sq * 48];
      #pragma unroll
      for (int i = 0; i < 48; i += 8)
        *reinterpret_cast<uint4*>(dst + i) = *reinterpret_cast<const uint4*>(src + i);
    }
    f32x4 acc[2][4];
    #pragma unroll
    for (int mf = 0; mf < 2; ++mf)
      #pragma unroll
      for (int nf = 0; nf < 4; ++nf) acc[mf][nf] = zz;
    #pragma unroll
    for (int kk = 0; kk < 6; ++kk){
      bf16x8 bfr[4];
      #pragma unroll
      for (int nf = 0; nf < 4; ++nf)
        bfr[nf] = *reinterpret_cast<const bf16x8*>(&Bl[cur][(nf * 16 + l15) * BPAD + kk * 32 + l4 * 8]);
      #pragma unroll
      for (int mf = 0; mf < 2; ++mf)
        #pragma unroll
        for (int nf = 0; nf < 4; ++nf)
          acc[mf][nf] = __builtin_amdgcn_mfma_f32_16x16x32_bf16(af[mf][kk], bfr[nf], acc[mf][nf], 0, 0, 0);
    }
    // epilogue: nt 0-2 -> Q, 3-5 -> K, 6-8 -> V (64-col tiles never straddle)
    int which = nt / 3;
    #pragma unroll
    for (int nf = 0; nf < 4; ++nf){
      int c = nt * 64 + nf * 16 + l15;
      int rem = c - which * CDIM;
      int hh = rem >> 5, chh = rem & 31;
      float bias = b1[c];
      if (which == 2){   // V transposed: n contiguous over r -> one uint2 store per quad
        #pragma unroll
        for (int mf = 0; mf < 2; ++mf){
          uint2 pv;
          pv.x = pk2(acc[mf][nf][0] + bias, acc[mf][nf][1] + bias);
          pv.y = pk2(acc[mf][nf][2] + bias, acc[mf][nf][3] + bias);
          *reinterpret_cast<uint2*>(vw + (((size_t)bw_[mf] * NH + hh) * CH + chh) * NTOK + n0_[mf]) = pv;
        }
      } else {
        u16* base = (which == 0) ? qw : kw;
        float mult = (which == 0) ? SCALE : 1.0f;
        #pragma unroll
        for (int mf = 0; mf < 2; ++mf)
          #pragma unroll
          for (int r = 0; r < 4; ++r)
            base[(((size_t)bw_[mf] * NH + hh) * NTOK + n0_[mf] + r) * CH + chh] = f2b((acc[mf][nf][r] + bias) * mult);
      }
    }
    cur ^= 1;
  }
}

// ---------------- K2: per (window, head) attention — no barriers, no staging LDS (proven R2).
extern "C" __global__ __launch_bounds__(192, 4) void attn_kernel(
    const u16* __restrict__ qw, const u16* __restrict__ kw, const u16* __restrict__ vw,
    const u16* __restrict__ comb, float* __restrict__ outbuf){
  __shared__ u16 Pl[3][16][40];   // per-wave P chunk, pad 40
  const int tid = threadIdx.x;
  const int bh = blockIdx.x;
  const int b = bh / NH, h = bh - b * NH;
  const int wv = tid >> 6, lane = tid & 63, l15 = lane & 15, l4 = lane >> 4;
  const size_t qkbase = ((size_t)b * NH + h) * (NTOK * CH);
  const size_t vbase  = ((size_t)b * NH + h) * (CH * NTOK);
  const size_t cbase  = ((size_t)((b / WLON) * NH + h)) * (5184 * 4);  // u16 units
  u16* Pw = &Pl[wv][0][0];
  u16* stash = reinterpret_cast<u16*>(outbuf);
  const f32x4 zz = {0.f, 0.f, 0.f, 0.f};

  for (int mi = 0; mi < 3; ++mi){
    const int ti = wv * 3 + mi;
    bf16x8 aq = *reinterpret_cast<const bf16x8*>(qw + qkbase + (ti * 16 + l15) * CH + l4 * 8);
    f32x4 s[9];
    #pragma unroll
    for (int nt = 0; nt < 9; ++nt){
      bf16x8 bk = *reinterpret_cast<const bf16x8*>(kw + qkbase + (nt * 16 + l15) * CH + l4 * 8);
      s[nt] = __builtin_amdgcn_mfma_f32_16x16x32_bf16(aq, bk, zz, 0, 0, 0);
    }
    #pragma unroll
    for (int nt = 0; nt < 9; ++nt){
      uint2 cc = *reinterpret_cast<const uint2*>(comb + cbase + ((size_t)(ti * 9 + nt) * 64 + lane) * 4);
      s[nt][0] += b2f((u16)(cc.x & 0xFFFF));
      s[nt][1] += b2f((u16)(cc.x >> 16));
      s[nt][2] += b2f((u16)(cc.y & 0xFFFF));
      s[nt][3] += b2f((u16)(cc.y >> 16));
    }
    float invs[4];
    #pragma unroll
    for (int r = 0; r < 4; ++r){
      float mx = s[0][r];
      #pragma unroll
      for (int nt = 1; nt < 9; ++nt) mx = fmaxf(mx, s[nt][r]);
      #pragma unroll
      for (int off = 8; off; off >>= 1) mx = fmaxf(mx, __shfl_xor(mx, off, 16));
      float sum = 0.f;
      #pragma unroll
      for (int nt = 0; nt < 9; ++nt){
        float p = exp2f((s[nt][r] - mx) * LOG2E);
        s[nt][r] = p; sum += p;
      }
      #pragma unroll
      for (int off = 8; off; off >>= 1) sum += __shfl_xor(sum, off, 16);
      invs[r] = 1.0f / sum;   // applied at stash
    }
    f32x4 o0 = zz, o1 = zz;
    #pragma unroll
    for (int kk = 0; kk < 5; ++kk){
      #pragma unroll
      for (int r = 0; r < 4; ++r){
        Pw[(l4 * 4 + r) * 40 + l15] = f2b(s[2 * kk][r]);
        if (kk < 4) Pw[(l4 * 4 + r) * 40 + 16 + l15] = f2b(s[2 * kk + 1][r]);
      }
      int j0 = kk * 32 + l4 * 8;
      int jc = (j0 < NTOK) ? j0 : 0;          // clamp tail address (stay in-bounds)
      bf16x8 ap = *reinterpret_cast<const bf16x8*>(Pw + l15 * 40 + l4 * 8);
      bf16x8 bv0 = *reinterpret_cast<const bf16x8*>(vw + vbase + (size_t)l15 * NTOK + jc);
      bf16x8 bv1 = *reinterpret_cast<const bf16x8*>(vw + vbase + (size_t)(16 + l15) * NTOK + jc);
      if (j0 >= NTOK) ap = bf16x8{0, 0, 0, 0, 0, 0, 0, 0};   // tail K=16: zero P side
      o0 = __builtin_amdgcn_mfma_f32_16x16x32_bf16(ap, bv0, o0, 0, 0, 0);
      o1 = __builtin_amdgcn_mfma_f32_16x16x32_bf16(ap, bv1, o1, 0, 0, 0);
    }
    #pragma unroll
    for (int r = 0; r < 4; ++r){
      size_t t = (size_t)b * NTOK + ti * 16 + l4 * 4 + r;
      float is = invs[r];
      stash[t * 384 + 192 + h * CH + l15]      = f2b(o0[r] * is);
      stash[t * 384 + 192 + h * CH + 16 + l15] = f2b(o1[r] * is);
    }
  }
}

// ---------------- K3: out = attn_out @ w2 + b2 — B register-stationary, one-deep A prefetch.
// Block = (256 rows x 96-col half). Each wave holds 36 w2t frags loaded once; streams 4 m-tiles.
extern "C" __global__ __launch_bounds__(256, 2) void proj_gemm(
    const u16* __restrict__ w2t, const float* __restrict__ b2, float* __restrict__ outbuf){
  const int tid = threadIdx.x;
  const int wid = tid >> 6, lane = tid & 63, l15 = lane & 15, l4 = lane >> 4;
  const int hb = blockIdx.y;             // col half: cols hb*96 .. +96
  const f32x4 zz = {0.f, 0.f, 0.f, 0.f};

  bf16x8 bfr[6][6];
  #pragma unroll
  for (int nf = 0; nf < 6; ++nf)
    #pragma unroll
    for (int kk = 0; kk < 6; ++kk)
      bfr[nf][kk] = *reinterpret_cast<const bf16x8*>(
          w2t + (size_t)(hb * 96 + nf * 16 + l15) * CDIM + kk * 32 + l4 * 8);

  const u16* stash = reinterpret_cast<const u16*>(outbuf);
  const size_t rbase = (size_t)blockIdx.x * 256 + wid * 64;

#define LOADA(dst, mt) { \
    const u16* src_ = stash + (rbase + (mt) * 16 + l15) * 384 + 192 + l4 * 8; \
    _Pragma("unroll") \
    for (int kk = 0; kk < 6; ++kk) dst[kk] = *reinterpret_cast<const bf16x8*>(src_ + kk * 32); }

#define COMPUTE(a_, mt) { \
    f32x4 acc[6]; \
    _Pragma("unroll") \
    for (int nf = 0; nf < 6; ++nf) acc[nf] = zz; \
    _Pragma("unroll") \
    for (int kk = 0; kk < 6; ++kk) \
      _Pragma("unroll") \
      for (int nf = 0; nf < 6; ++nf) \
        acc[nf] = __builtin_amdgcn_mfma_f32_16x16x32_bf16(a_[kk], bfr[nf][kk], acc[nf], 0, 0, 0); \
    _Pragma("unroll") \
    for (int nf = 0; nf < 6; ++nf){ \
      int c = hb * 96 + nf * 16 + l15; \
      float bias = b2[c]; \
      _Pragma("unroll") \
      for (int r = 0; r < 4; ++r) \
        outbuf[(rbase + (mt) * 16 + l4 * 4 + r) * CDIM + c] = acc[nf][r] + bias; } }

  bf16x8 a0[6], a1[6];
  LOADA(a0, 0)
  LOADA(a1, 1) COMPUTE(a0, 0)
  LOADA(a0, 2) COMPUTE(a1, 1)
  LOADA(a1, 3) COMPUTE(a0, 2)
  COMPUTE(a1, 3)
#undef LOADA
#undef COMPUTE
}

extern "C" void kernel_launch(void* const* d_in, const int* in_sizes, int n_in,
                              void* d_out, int out_size, void* d_ws, size_t ws_size,
                              hipStream_t stream){
  const float* x    = (const float*)d_in[0];
  const float* w1   = (const float*)d_in[1];
  const float* b1   = (const float*)d_in[2];
  const float* w2   = (const float*)d_in[3];
  const float* b2   = (const float*)d_in[4];
  const float* bt   = (const float*)d_in[5];
  const float* mask = (const float*)d_in[6];
  const int*   pidx = (const int*)d_in[7];
  (void)in_sizes; (void)n_in; (void)out_size; (void)ws_size;

  char* ws = (char*)d_ws;
  u16* w1t  = (u16*)(ws + OFF_W1T);
  u16* w2t  = (u16*)(ws + OFF_W2T);
  u16* comb = (u16*)(ws + OFF_COMB);
  u16* qw   = (u16*)(ws + OFF_Q);
  u16* kw   = (u16*)(ws + OFF_K);
  u16* vw   = (u16*)(ws + OFF_V);
  float* out = (float*)d_out;

  prep_weights<<<dim3(432), dim3(256), 0, stream>>>(w1, w2, w1t, w2t);
  prep_comb<<<dim3(384, 27), dim3(192), 0, stream>>>(bt, mask, pidx, comb);
  qkv_gemm<<<dim3(1080), dim3(256), 0, stream>>>(x, w1t, b1, qw, kw, vw);
  attn_kernel<<<dim3(5760), dim3(192), 0, stream>>>(qw, kw, vw, comb, out);
  proj_gemm<<<dim3(540, 2), dim3(256), 0, stream>>>(w2t, b2, out);
}